// Round 11
// baseline (292.683 us; speedup 1.0000x reference)
//
#include <hip/hip_runtime.h>
#include <hip/hip_bf16.h>

#define BATCH 8
#define CIN   128
#define HH    256
#define WW    256
#define OUTC  64
#define INCH  1152   // CIN*9
#define HW    (HH*WW)

#define CSTRIDE    ((size_t)HH * WW * 64)                 // bytes per (b,chunk) plane
#define XC_BYTES   ((size_t)BATCH * 4 * CSTRIDE)          // 134217728
#define WMOD_BYTES ((size_t)BATCH * 9 * OUTC * CIN * 2)   // 1179648
#define Z_BYTES    64

typedef __attribute__((ext_vector_type(8))) short short8;
typedef __attribute__((ext_vector_type(4))) float f32x4;
typedef __attribute__((ext_vector_type(2))) float f32x2;
typedef __attribute__((ext_vector_type(4))) unsigned int u32x4;

__device__ __forceinline__ unsigned short bf16r(float f) {
    unsigned u = __builtin_bit_cast(unsigned, f);
    u += 0x7fffu + ((u >> 16) & 1u);
    return (unsigned short)(u >> 16);
}

__device__ __forceinline__ void gload16(const void* src, void* dst_lds) {
    __builtin_amdgcn_global_load_lds(
        (const __attribute__((address_space(1))) unsigned int*)src,
        (__attribute__((address_space(3))) unsigned int*)dst_lds,
        16, 0, 0);
}

// wmod[b][tap][o][c] = bf16(weight[o][c*9+tap] * style[b][c*9+tap])
__global__ void __launch_bounds__(256) wmod_kernel(const float* __restrict__ weight,
                                                   const float* __restrict__ style,
                                                   unsigned short* __restrict__ wmod) {
    int i = blockIdx.x * 256 + threadIdx.x;
    if (i >= BATCH * 9 * OUTC * CIN) return;
    int c    = i & (CIN - 1);
    int rest = i >> 7;
    int o    = rest & (OUTC - 1);
    int bt   = rest >> 6;
    int tap  = bt % 9;
    int b    = bt / 9;
    int k    = c * 9 + tap;
    wmod[i] = bf16r(weight[o * INCH + k] * style[b * INCH + k]);
}

// xC[b][chunk][h][w][c32]: 64B per (pixel, 32-ch chunk), pixels contiguous in w.
// Block 256 thr: lane = w-pair, tid>>6 = chunk. Reads f32x2 per channel
// (512B/instr coalesced); writes 2x64B contiguous per thread.
__global__ void __launch_bounds__(256) repack_kernel(const float* __restrict__ x,
                                                     unsigned short* __restrict__ xC) {
    const int w  = blockIdx.x * 128 + (threadIdx.x & 63) * 2;
    const int ck = threadIdx.x >> 6;       // chunk 0..3
    const int h  = blockIdx.y;
    const int b  = blockIdx.z;

    const float* xp = x + ((size_t)(b * CIN + ck * 32)) * HW + h * WW + w;
    unsigned short* op = xC + ((size_t)(b * 4 + ck) * HH + h) * ((size_t)WW * 32) +
                         (size_t)w * 32;

    f32x2 f[32];
#pragma unroll
    for (int j = 0; j < 32; ++j) f[j] = *(const f32x2*)(xp + (size_t)j * HW);

#pragma unroll
    for (int u = 0; u < 2; ++u) {
        unsigned pk[16];
#pragma unroll
        for (int j = 0; j < 16; ++j)
            pk[j] = (unsigned)bf16r(f[2 * j][u]) |
                    ((unsigned)bf16r(f[2 * j + 1][u]) << 16);
#pragma unroll
        for (int q = 0; q < 4; ++q) {
            u32x4 v = {pk[q * 4 + 0], pk[q * 4 + 1], pk[q * 4 + 2], pk[q * 4 + 3]};
            *(u32x4*)(op + u * 32 + q * 8) = v;
        }
    }
}

// conv6: block 256 thr = 4 waves (wr=o-half, wc=w-half); tile 64o x (4h x 32w).
// LDS xs[2][204*64B]: granule G = s*4+cg, addr = G*16 (LINEAR — G-order is
// contiguous in xC, so gload_lds is 1KB/instr coalesced; B-read pattern
// s*64+kg*16 is bank-balanced: 8 lanes per 4-bank group, full LDS BW).
// Per chunk: stage(k+1) [3-4 gload_lds, no VGPRs] -> compute(k) [zero VMEM:
// A preloaded, LDS+MFMA only -> no vmcnt drain] -> loadA(k+1) -> barrier.
__global__ void __launch_bounds__(256, 3) conv6_kernel(
    const unsigned short* __restrict__ xC,
    const unsigned short* __restrict__ wmod,
    const unsigned short* __restrict__ zptr,
    float* __restrict__ out)
{
    __shared__ __align__(16) unsigned short xs_sm[2][204 * 32];

    const int tid = threadIdx.x;           // 0..255
    const int bx  = blockIdx.x;            // 0..511: ht*8 + wt
    const int b   = blockIdx.y;
    const int h0  = (bx >> 3) * 4;
    const int w0  = (bx & 7) * 32;

    const int wv  = tid >> 6;
    const int wr  = wv >> 1;               // o-half
    const int wc  = wv & 1;                // w-half
    const int l15 = tid & 15;
    const int kg  = (tid >> 4) & 3;

    // ---- staging geometry: granule G = tid + i*256 (G < 816), G = s*4+cg
    const char* xCb = (const char*)xC + (size_t)b * 4 * CSTRIDE;
    int  soff[4];
    bool sok[4];
#pragma unroll
    for (int i = 0; i < 4; ++i) {
        int G  = tid + i * 256;
        int Gc = (G < 816) ? G : 0;
        int s  = Gc >> 2;
        int cg = Gc & 3;
        int r   = s / 34;
        int col = s - r * 34;
        int h = h0 - 1 + r, w = w0 - 1 + col;
        sok[i]  = (G < 816) && ((unsigned)h < HH) && ((unsigned)w < WW);
        soff[i] = (h * WW + w) * 64 + cg * 16;
    }

    f32x4 acc[2][4];
#pragma unroll
    for (int mi = 0; mi < 2; ++mi)
#pragma unroll
        for (int ni = 0; ni < 4; ++ni) acc[mi][ni] = (f32x4){0.f, 0.f, 0.f, 0.f};

    short8 A[9][2];

    auto stage = [&](int chunk, int bufsel) {
        char* base = (char*)&xs_sm[bufsel][0];
#pragma unroll
        for (int i = 0; i < 4; ++i) {
            if (i < 3 || tid < 48) {
                const void* src = sok[i]
                    ? (const void*)(xCb + (size_t)chunk * CSTRIDE + soff[i])
                    : (const void*)zptr;
                gload16(src, base + (size_t)(i * 256 + tid) * 16);
            }
        }
    };

    auto loadA = [&](int chunk) {
        const unsigned short* wb =
            wmod + ((size_t)(b * 9) * OUTC) * CIN + chunk * 32 + kg * 8;
#pragma unroll
        for (int tap = 0; tap < 9; ++tap)
#pragma unroll
            for (int mi = 0; mi < 2; ++mi)
                A[tap][mi] = *(const short8*)(
                    wb + ((size_t)tap * OUTC + wr * 32 + mi * 16 + l15) * CIN);
    };

    auto compute = [&](const unsigned short* buf) {
#pragma unroll
        for (int kh = 0; kh < 3; ++kh)
#pragma unroll
            for (int kw = 0; kw < 3; ++kw) {
                const int tap = kh * 3 + kw;
                short8 Bv[4];
#pragma unroll
                for (int ni = 0; ni < 4; ++ni) {
                    int s = (ni + kh) * 34 + wc * 16 + l15 + kw;
                    Bv[ni] = *(const short8*)&buf[s * 32 + kg * 8];
                }
#pragma unroll
                for (int mi = 0; mi < 2; ++mi)
#pragma unroll
                    for (int ni = 0; ni < 4; ++ni)
                        acc[mi][ni] = __builtin_amdgcn_mfma_f32_16x16x32_bf16(
                            A[tap][mi], Bv[ni], acc[mi][ni], 0, 0, 0);
            }
    };

    // ---- pipeline: stage(k+1) || compute(k), A preloaded per chunk
    stage(0, 0);
    loadA(0);
    __syncthreads();

    stage(1, 1);
    __builtin_amdgcn_sched_barrier(0);
    compute(xs_sm[0]);
    __builtin_amdgcn_sched_barrier(0);
    loadA(1);
    __syncthreads();

    stage(2, 0);
    __builtin_amdgcn_sched_barrier(0);
    compute(xs_sm[1]);
    __builtin_amdgcn_sched_barrier(0);
    loadA(2);
    __syncthreads();

    stage(3, 1);
    __builtin_amdgcn_sched_barrier(0);
    compute(xs_sm[0]);
    __builtin_amdgcn_sched_barrier(0);
    loadA(3);
    __syncthreads();

    compute(xs_sm[1]);

    // ---- epilogue: D mapping col=lane&15 (pixel), row=(lane>>4)*4+r (o)
    float* op = out + ((size_t)b * OUTC) * HW + (size_t)h0 * WW + w0 + wc * 16 + l15;
#pragma unroll
    for (int mi = 0; mi < 2; ++mi)
#pragma unroll
        for (int ni = 0; ni < 4; ++ni)
#pragma unroll
            for (int rr = 0; rr < 4; ++rr) {
                int o = wr * 32 + mi * 16 + kg * 4 + rr;
                op[(size_t)o * HW + ni * WW] = acc[mi][ni][rr];
            }
}

// ---------------- fallback conv (round-7 path, fp32 staging) ----------------
template <bool GW>
__global__ void __launch_bounds__(512, 4) conv_kernel(
    const float* __restrict__ x,
    const unsigned short* __restrict__ wmod,
    const float* __restrict__ weight,
    const float* __restrict__ style,
    float* __restrict__ out)
{
    __shared__ __align__(16) unsigned short xs_sm[170 * 64];

    const int tid = threadIdx.x;
    const int bx  = blockIdx.x;
    const int b   = blockIdx.y;
    const int h0  = (bx >> 3) * 8;
    const int w0  = (bx & 7) * 32;

    const int wv  = tid >> 6;
    const int wr  = wv >> 2;
    const int wc  = wv & 3;
    const int l15 = tid & 15;
    const int kg  = (tid >> 4) & 3;

    int sbase[4];
#pragma unroll
    for (int ni = 0; ni < 4; ++ni) {
        int p = wc * 64 + ni * 16 + l15;
        sbase[ni] = (p >> 5) * 34 + (p & 31);
    }

    const bool tvalid = tid < 400;
    const int scg = tvalid ? tid / 100 : 0;
    const int srw = tvalid ? tid % 100 : 0;
    const int sr  = srw / 10;
    const int swq = srw % 10;
    const int sh  = h0 - 1 + sr;
    const bool hok = (unsigned)sh < HH;
    const int wload  = w0 - 4 + swq * 4;
    const int wclamp = min(max(wload, 0), WW - 4);
    const int gbase  = (hok ? sh : 0) * WW + wclamp;

    f32x4 acc[2][4];
#pragma unroll
    for (int mi = 0; mi < 2; ++mi)
#pragma unroll
        for (int ni = 0; ni < 4; ++ni) acc[mi][ni] = (f32x4){0.f, 0.f, 0.f, 0.f};

    for (int chunk = 0; chunk < 4; ++chunk) {
        if (chunk) __syncthreads();

        if (tvalid) {
            const float* xp =
                x + ((size_t)(b * CIN + chunk * 32 + scg * 8)) * HW + gbase;
            f32x4 f[8];
#pragma unroll
            for (int j = 0; j < 8; ++j)
                f[j] = hok ? *(const f32x4*)(xp + (size_t)j * HW)
                           : (f32x4){0.f, 0.f, 0.f, 0.f};
#pragma unroll
            for (int u = 0; u < 4; ++u) {
                int w   = wload + u;
                int col = w - (w0 - 1);
                if (col >= 0 && col <= 33) {
                    bool wok = hok && ((unsigned)w < WW);
                    short8 sv;
#pragma unroll
                    for (int j = 0; j < 8; ++j)
                        sv[j] = wok ? (short)bf16r(f[j][u]) : (short)0;
                    int s = sr * 34 + col;
                    int q = s >> 1;
                    int g = (((s & 1) << 2) | scg) ^ (q & 7);
                    *(short8*)&xs_sm[q * 64 + g * 8] = sv;
                }
            }
        }
        __syncthreads();

        const unsigned short* wmb = wmod + ((size_t)(b * 9) * OUTC) * CIN + chunk * 32;
#pragma unroll
        for (int tap = 0; tap < 9; ++tap) {
            const int kh = tap / 3, kw = tap % 3;

            short8 A[2];
            if (GW) {
                const unsigned short* wt = wmb + (size_t)tap * OUTC * CIN;
#pragma unroll
                for (int mi = 0; mi < 2; ++mi)
                    A[mi] = *(const short8*)(wt + (wr * 32 + mi * 16 + l15) * CIN +
                                             kg * 8);
            } else {
#pragma unroll
                for (int mi = 0; mi < 2; ++mi) {
                    int o = wr * 32 + mi * 16 + l15;
#pragma unroll
                    for (int j = 0; j < 8; ++j) {
                        int c = chunk * 32 + kg * 8 + j;
                        int k = c * 9 + tap;
                        A[mi][j] = (short)bf16r(weight[o * INCH + k] *
                                                style[b * INCH + k]);
                    }
                }
            }

            short8 Bv[4];
#pragma unroll
            for (int ni = 0; ni < 4; ++ni) {
                int s = sbase[ni] + kh * 34 + kw;
                int q = s >> 1;
                int g = (((s & 1) << 2) | kg) ^ (q & 7);
                Bv[ni] = *(const short8*)&xs_sm[q * 64 + g * 8];
            }
#pragma unroll
            for (int mi = 0; mi < 2; ++mi)
#pragma unroll
                for (int ni = 0; ni < 4; ++ni)
                    acc[mi][ni] = __builtin_amdgcn_mfma_f32_16x16x32_bf16(
                        A[mi], Bv[ni], acc[mi][ni], 0, 0, 0);
        }
    }

    float* op = out + ((size_t)b * OUTC) * HW;
#pragma unroll
    for (int mi = 0; mi < 2; ++mi) {
#pragma unroll
        for (int ni = 0; ni < 4; ++ni) {
            int p = wc * 64 + ni * 16 + l15;
            int h = h0 + (p >> 5), w = w0 + (p & 31);
#pragma unroll
            for (int r = 0; r < 4; ++r) {
                int o = wr * 32 + mi * 16 + kg * 4 + r;
                op[(size_t)o * HW + h * WW + w] = acc[mi][ni][r];
            }
        }
    }
}

extern "C" void kernel_launch(void* const* d_in, const int* in_sizes, int n_in,
                              void* d_out, int out_size, void* d_ws, size_t ws_size,
                              hipStream_t stream) {
    const float* x      = (const float*)d_in[0];
    const float* style  = (const float*)d_in[1];
    const float* weight = (const float*)d_in[2];
    float* out = (float*)d_out;

    const int wmod_total = BATCH * 9 * OUTC * CIN;

    if (ws_size >= XC_BYTES + WMOD_BYTES + Z_BYTES) {
        unsigned short* xC    = (unsigned short*)d_ws;
        unsigned short* wmodp = (unsigned short*)((char*)d_ws + XC_BYTES);
        unsigned short* zptr  = (unsigned short*)((char*)d_ws + XC_BYTES + WMOD_BYTES);

        wmod_kernel<<<(wmod_total + 255) / 256, 256, 0, stream>>>(weight, style, wmodp);
        hipMemsetAsync(zptr, 0, Z_BYTES, stream);
        repack_kernel<<<dim3(2, HH, BATCH), 256, 0, stream>>>(x, xC);
        conv6_kernel<<<dim3(512, BATCH), 256, 0, stream>>>(xC, wmodp, zptr, out);
    } else if (ws_size >= WMOD_BYTES) {
        unsigned short* wmodp = (unsigned short*)d_ws;
        wmod_kernel<<<(wmod_total + 255) / 256, 256, 0, stream>>>(weight, style, wmodp);
        conv_kernel<true><<<dim3(256, BATCH), 512, 0, stream>>>(
            x, wmodp, nullptr, nullptr, out);
    } else {
        conv_kernel<false><<<dim3(256, BATCH), 512, 0, stream>>>(
            x, nullptr, weight, style, out);
    }
}